// Round 11
// baseline (412.279 us; speedup 1.0000x reference)
//
#include <hip/hip_runtime.h>
#include <hip/hip_fp16.h>

#define NNODES   4000
#define TSTEPS   32
#define HDIM     64
#define ECOUNT   1024000
#define NTOT     128000        // NNODES * TSTEPS
#define BATCHB   8
#define NNEUR    500
#define TEBD     16
#define NSTEPS   12

#define REC_BLOCKS  (NNODES / 16)    // 250

// ---------------- main (M-GEMM) pipeline geometry ----------------
#define HISTF_BLOCKS (ECOUNT / 256)  // 4000 fire-and-forget dw blocks
#define ZERO_BLOCKS  2000            // 2000 x 32 KB = 65,536,000 B = sizeof(M)
#define NBT          256
#define MBYTES       ((size_t)NTOT * NBT * 2)          // 65.536 MB u16 fixed-point
#define MB_BLOCKS    (ECOUNT / 256)  // 4000
#define SCALE_BLOCKS (NTOT * HDIM / 8 / 256)           // 4000
#define GEMM_BLOCKS  256
#define CHUNK_SRC    (NTOT / GEMM_BLOCKS)              // 500
#define PPART        (NBT * HDIM)                      // 16384 floats / block
#define MAIN_WS      (512000 + 65536 + 65536000 + 16777216 + 16384000)  // 99.27 MB

// ---------------- fallback (r6 bucket) pipeline geometry ----------------
#define CNT_SHIFT 23
#define SUM_MASK  0x7FFFFFu
#define SUM_SCALE 262144.0f
#define SLOTS     32
#define HIST_BLOCKS (ECOUNT / 256)
#define ROWS_PER_WAVE  5
#define ROWS_PER_BLOCK 20
#define GATHER_BLOCKS  (NTOT / ROWS_PER_BLOCK)

typedef _Float16 half8_t __attribute__((ext_vector_type(8)));
typedef _Float16 half2_t __attribute__((ext_vector_type(2)));
typedef float    f32x4_t __attribute__((ext_vector_type(4)));

__device__ __forceinline__ float sigmoidf_(float x) {
    return 1.0f / (1.0f + __expf(-x));
}
__device__ __forceinline__ float tanhf_(float x) {
    return 1.0f - 2.0f / (1.0f + __expf(2.0f * x));
}

// ======== shared GRU recurrence body (identical math in both pipelines) ====
// One block (4 waves) owns 16 nodes for all 32 timesteps; wave wv owns the
// 16-feature stripe of each gate. Weight B-frags in VGPRs; LDS only a
// 2x(16x72) fp16 ping-pong for the C->A h transpose; 1 barrier/step.
// Fragment layouts (gfx950 16x16x32): A[m=lane&15][k=quad*8+j],
// B[k=quad*8+j][n=lane&15], C[m=quad*4+reg][n=lane&15].
__device__ __forceinline__ void gru_body(
    const float* __restrict__ x, const float* __restrict__ Wih,
    const float* __restrict__ Whh, const float* __restrict__ bih,
    const float* __restrict__ bhh, const float* __restrict__ Wg,
    _Float16* __restrict__ xwh, _Float16 (*hbuf)[16 * 72], int tid, int blk)
{
    const int lane = tid & 63;
    const int wv   = tid >> 6;
    const int c    = lane & 15;
    const int quad = lane >> 4;
    const int n0   = blk * 16;

    auto makeB = [&](const float* W, int row, int k0) -> half8_t {
        const float4* p = (const float4*)(W + (size_t)row * HDIM + k0);
        float4 u = p[0], v = p[1];
        half8_t h;
        h[0] = (_Float16)u.x; h[1] = (_Float16)u.y; h[2] = (_Float16)u.z; h[3] = (_Float16)u.w;
        h[4] = (_Float16)v.x; h[5] = (_Float16)v.y; h[6] = (_Float16)v.z; h[7] = (_Float16)v.w;
        return h;
    };

    half8_t Bxr[2], Bxz[2], Bxn[2], Bhr[2], Bhz[2], Bhn[2], Bw[2];
#pragma unroll
    for (int kt = 0; kt < 2; ++kt) {
        int k0 = kt * 32 + quad * 8;
        Bxr[kt] = makeB(Wih, wv * 16 + c, k0);
        Bxz[kt] = makeB(Wih, 64 + wv * 16 + c, k0);
        Bxn[kt] = makeB(Wih, 128 + wv * 16 + c, k0);
        Bhr[kt] = makeB(Whh, wv * 16 + c, k0);
        Bhz[kt] = makeB(Whh, 64 + wv * 16 + c, k0);
        Bhn[kt] = makeB(Whh, 128 + wv * 16 + c, k0);
        Bw[kt]  = makeB(Wg, wv * 16 + c, k0);
    }

    const int f = wv * 16 + c;
    const float brz_r = bih[f] + bhh[f];
    const float brz_z = bih[64 + f] + bhh[64 + f];
    const float bin_  = bih[128 + f];
    const float bhn_  = bhh[128 + f];

    float hreg[4] = {0.f, 0.f, 0.f, 0.f};
    half8_t ah[2];

    const float* xp = x + (size_t)(n0 + c) * (TSTEPS * HDIM) + quad * 8;

    float4 xq0[4], xq1[4];
    {
        const float* p0 = xp;
        xq0[0] = *(const float4*)(p0);      xq0[1] = *(const float4*)(p0 + 4);
        xq0[2] = *(const float4*)(p0 + 32); xq0[3] = *(const float4*)(p0 + 36);
        const float* p1 = xp + HDIM;
        xq1[0] = *(const float4*)(p1);      xq1[1] = *(const float4*)(p1 + 4);
        xq1[2] = *(const float4*)(p1 + 32); xq1[3] = *(const float4*)(p1 + 36);
    }

    auto step = [&](int t, float4* xq) {
        half8_t ax[2];
#pragma unroll
        for (int kt = 0; kt < 2; ++kt) {
            float4 u = xq[kt * 2], v = xq[kt * 2 + 1];
            half8_t a;
            a[0] = (_Float16)u.x; a[1] = (_Float16)u.y; a[2] = (_Float16)u.z; a[3] = (_Float16)u.w;
            a[4] = (_Float16)v.x; a[5] = (_Float16)v.y; a[6] = (_Float16)v.z; a[7] = (_Float16)v.w;
            ax[kt] = a;
        }
        if (t + 2 < TSTEPS) {
            const float* pt = xp + (size_t)(t + 2) * HDIM;
            xq[0] = *(const float4*)(pt);      xq[1] = *(const float4*)(pt + 4);
            xq[2] = *(const float4*)(pt + 32); xq[3] = *(const float4*)(pt + 36);
        }

        f32x4_t Cr  = (f32x4_t){0.f, 0.f, 0.f, 0.f};
        f32x4_t Cz  = (f32x4_t){0.f, 0.f, 0.f, 0.f};
        f32x4_t Cnx = (f32x4_t){0.f, 0.f, 0.f, 0.f};
        f32x4_t Cnh = (f32x4_t){0.f, 0.f, 0.f, 0.f};

#pragma unroll
        for (int kt = 0; kt < 2; ++kt) {
            Cr  = __builtin_amdgcn_mfma_f32_16x16x32_f16(ax[kt], Bxr[kt], Cr, 0, 0, 0);
            Cz  = __builtin_amdgcn_mfma_f32_16x16x32_f16(ax[kt], Bxz[kt], Cz, 0, 0, 0);
            Cnx = __builtin_amdgcn_mfma_f32_16x16x32_f16(ax[kt], Bxn[kt], Cnx, 0, 0, 0);
        }
        if (t > 0) {
#pragma unroll
            for (int kt = 0; kt < 2; ++kt) {
                Cr  = __builtin_amdgcn_mfma_f32_16x16x32_f16(ah[kt], Bhr[kt], Cr, 0, 0, 0);
                Cz  = __builtin_amdgcn_mfma_f32_16x16x32_f16(ah[kt], Bhz[kt], Cz, 0, 0, 0);
                Cnh = __builtin_amdgcn_mfma_f32_16x16x32_f16(ah[kt], Bhn[kt], Cnh, 0, 0, 0);
            }
        }

        _Float16* hb = hbuf[t & 1];
#pragma unroll
        for (int r = 0; r < 4; ++r) {
            float rr = sigmoidf_(Cr[r] + brz_r);
            float zz = sigmoidf_(Cz[r] + brz_z);
            float nn = tanhf_(Cnx[r] + bin_ + rr * (Cnh[r] + bhn_));
            float hn = (1.0f - zz) * nn + zz * hreg[r];
            hreg[r] = hn;
            hb[(quad * 4 + r) * 72 + f] = (_Float16)hn;
        }

        __syncthreads();

#pragma unroll
        for (int kt = 0; kt < 2; ++kt)
            ah[kt] = *(half8_t*)&hb[c * 72 + kt * 32 + quad * 8];

        f32x4_t Cw = (f32x4_t){0.f, 0.f, 0.f, 0.f};
#pragma unroll
        for (int kt = 0; kt < 2; ++kt)
            Cw = __builtin_amdgcn_mfma_f32_16x16x32_f16(ah[kt], Bw[kt], Cw, 0, 0, 0);

#pragma unroll
        for (int r = 0; r < 4; ++r) {
            int row = (n0 + quad * 4 + r) * TSTEPS + t;
            xwh[(size_t)row * HDIM + f] = (_Float16)Cw[r];
        }
    };

#pragma unroll 1
    for (int tt = 0; tt < TSTEPS; tt += 2) {
        step(tt, xq0);
        step(tt + 1, xq1);
    }
}

// =================== MAIN PIPELINE (M-matrix GEMM) =========================
// S[bt][h] = sum_s M[s][bt] * xws[s][h] + sum_{d in bt} dis[d]*xws[d][h],
// M[s][bt] = sum_{e:(s->d), d in bt} w_e*dis[d], xws = dis[s]*xwh.
// M cells are u16 fixed-point 2^-12 packed in u32 words: built with plain
// u32 atomicAdd (fire-and-forget; round-10's __half2 atomic doesn't exist
// on ROCm 7.2). Cross-half carry needs a cell sum >= 2^16 = 16 max-weight
// edges in one cell (occupancy Poisson(0.03)): probability ~0.

// -------- fused: GRU (0..249) + fire-forget dw hist (250..4249) +
//          M zeroing (4250..6249, co-scheduled streaming writes) ----------
__global__ __launch_bounds__(256) void k_recHZ(
    const float* __restrict__ x, const float* __restrict__ Wih,
    const float* __restrict__ Whh, const float* __restrict__ bih,
    const float* __restrict__ bhh, const float* __restrict__ Wg,
    _Float16* __restrict__ xwh,
    const int* __restrict__ ei, const float* __restrict__ ea,
    float* __restrict__ dw, uint4* __restrict__ Mz)
{
    __shared__ __align__(16) _Float16 hbuf[2][16 * 72];
    const int tid = threadIdx.x;

    if (blockIdx.x >= REC_BLOCKS + HISTF_BLOCKS) {
        // M-zero family: 32 KB / block, pure streaming
        const int zb = blockIdx.x - (REC_BLOCKS + HISTF_BLOCKS);
        uint4* p = Mz + (size_t)zb * 2048;
        uint4 z; z.x = 0; z.y = 0; z.z = 0; z.w = 0;
#pragma unroll
        for (int i = 0; i < 8; ++i) p[i * 256 + tid] = z;
        return;
    }
    if (blockIdx.x >= REC_BLOCKS) {
        // degree histogram: 1 edge/thread, fire-and-forget (no return value)
        int e = (blockIdx.x - REC_BLOCKS) * 256 + tid;
        atomicAdd(&dw[ei[ECOUNT + e]], ea[e]);
        return;
    }
    gru_body(x, Wih, Whh, bih, bhh, Wg, xwh, hbuf, tid, blockIdx.x);
}

// -------- in-place pre-scale: xwh[r][:] *= dis[r],  dis = rsqrt(1+dw) -----
__global__ __launch_bounds__(256) void k_scaleF(
    _Float16* __restrict__ xwh, const float* __restrict__ dw)
{
    const int t = blockIdx.x * 256 + threadIdx.x;
    const int row = t >> 3;
    const float dd = rsqrtf(1.0f + dw[row]);
    half8_t v = *(half8_t*)&xwh[(size_t)t * 8];
#pragma unroll
    for (int i = 0; i < 8; ++i) v[i] = (_Float16)((float)v[i] * dd);
    *(half8_t*)&xwh[(size_t)t * 8] = v;
}

// -------- M build: one fire-and-forget u32 atomic per edge ----------------
// M layout [s][bt] (row 512 B) so the GEMM reads it sequentially. Cell
// = u16 half (bt&1) of u32 word s*128 + bt/2, fixed-point 2^-12
// (c <= 1 -> fx <= 4096; quantization 1.2e-4 << fp16 xwh noise).
// No rank, no returned value, no ordering.
__global__ __launch_bounds__(256) void k_Mbuild(
    const int* __restrict__ ei, const float* __restrict__ ea,
    const float* __restrict__ dw, unsigned* __restrict__ M32)
{
    int e = blockIdx.x * 256 + threadIdx.x;
    int s = ei[e], d = ei[ECOUNT + e];
    float c = ea[e] * rsqrtf(1.0f + dw[d]);
    unsigned bt = (unsigned)d / 500u;
    unsigned fx = (unsigned)(c * 4096.0f + 0.5f);
    unsigned val = (bt & 1u) ? (fx << 16) : fx;
    atomicAdd(&M32[(size_t)s * 128 + (bt >> 1)], val);
}

// -------- dense GEMM: Ppart[blk][bt][h] = sum_{s in chunk} M[s][bt]*xws[s][h]
// 256 blocks x 512 threads (tid&255 = bt, tid>>8 = h-half). No LDS, no
// barriers: xws row segments are wave-uniform (1-line broadcast loads,
// L1/L2-resident 64 KB chunk); M is read as per-block SEQUENTIAL 256 KB
// streams, 2 B/lane coalesced. Inner product in half2 v_pk_fma_f16 (2
// MACs/cycle/lane): 97% of M cells are zero and fma(0,x,acc) is exact, so
// fp16 acc error comes only from the ~16 real terms per output (~2e-3).
// 4-src unroll for MLP.
__global__ __launch_bounds__(512) void k_gemm(
    const _Float16* __restrict__ xws, const unsigned short* __restrict__ Mu,
    float* __restrict__ Ppart)
{
    const int tid = threadIdx.x;
    const int bt  = tid & 255;
    const int hh  = tid >> 8;            // h-half 0/1
    const int base = blockIdx.x * CHUNK_SRC;

    half2_t acc2[16];
#pragma unroll
    for (int j = 0; j < 16; ++j) acc2[j] = (half2_t){(_Float16)0.f, (_Float16)0.f};

#pragma unroll 1
    for (int b = 0; b < CHUNK_SRC; b += 4) {
#pragma unroll
        for (int u = 0; u < 4; ++u) {
            const int sidx = base + b + u;
            unsigned short cell = Mu[(size_t)sidx * NBT + bt];
            _Float16 mh = (_Float16)((float)cell * 0x1p-12f);
            half2_t m2 = (half2_t){mh, mh};
            const half2_t* xr = (const half2_t*)&xws[(size_t)sidx * HDIM + hh * 32];
#pragma unroll
            for (int j = 0; j < 16; ++j)
                acc2[j] += m2 * xr[j];           // v_pk_fma_f16
        }
    }

    float* dst = Ppart + (size_t)blockIdx.x * PPART + bt * HDIM + hh * 32;
#pragma unroll
    for (int j = 0; j < 16; j += 2) {
        f32x4_t f;
        f[0] = (float)acc2[j][0];     f[1] = (float)acc2[j][1];
        f[2] = (float)acc2[j + 1][0]; f[3] = (float)acc2[j + 1][1];
        *(f32x4_t*)&dst[j * 2] = f;
    }
}

// -------- merge partials + self-loops into S ------------------------------
__global__ __launch_bounds__(256) void k_mergeM(
    const float* __restrict__ Ppart, const _Float16* __restrict__ xws,
    const float* __restrict__ dw, float* __restrict__ S)
{
    const int bt  = blockIdx.x;
    const int tid = threadIdx.x;
    const int h   = tid & 63;
    const int q   = tid >> 6;

    float s = 0.f;
    const float* bp = Ppart + (size_t)bt * HDIM + h;
#pragma unroll 4
    for (int c = q * 64; c < q * 64 + 64; ++c)
        s += bp[(size_t)c * PPART];

    const int dbase = bt * NNEUR + q * 125;      // self: dis^2*xw = dis*xws
#pragma unroll 1
    for (int r = 0; r < 125; ++r) {
        int d = dbase + r;
        s += rsqrtf(1.0f + dw[d]) * (float)xws[(size_t)d * HDIM + h];
    }

    __shared__ float red[256];
    red[tid] = s;
    __syncthreads();
    if (tid < 64)
        S[bt * 64 + tid] = red[tid] + red[64 + tid] + red[128 + tid] + red[192 + tid];
}

// =================== FALLBACK PIPELINE (r6, 228.9 us) ======================
__global__ __launch_bounds__(256) void k_recHist(
    const float* __restrict__ x, const float* __restrict__ Wih,
    const float* __restrict__ Whh, const float* __restrict__ bih,
    const float* __restrict__ bhh, const float* __restrict__ Wg,
    _Float16* __restrict__ xwh,
    const int* __restrict__ ei, const float* __restrict__ ea,
    unsigned* __restrict__ dc, unsigned* __restrict__ se32)
{
    __shared__ __align__(16) _Float16 hbuf[2][16 * 72];
    const int tid = threadIdx.x;

    if (blockIdx.x >= REC_BLOCKS) {
        int e = (blockIdx.x - REC_BLOCKS) * 256 + tid;
        int s = ei[e], d = ei[ECOUNT + e];
        float w = ea[e];
        unsigned q = (unsigned)(w * 32768.0f + 0.5f); q = q > 32767u ? 32767u : q;
        unsigned fx = (unsigned)(w * SUM_SCALE + 0.5f);
        unsigned old = atomicAdd(&dc[d], (1u << CNT_SHIFT) | fx);
        int r = (int)(old >> CNT_SHIFT);
        if (r < SLOTS)
            se32[d * SLOTS + r] = ((unsigned)s << 15) | q;
        return;
    }
    gru_body(x, Wih, Whh, bih, bhh, Wg, xwh, hbuf, tid, blockIdx.x);
}

__global__ __launch_bounds__(256) void k_scale(
    _Float16* __restrict__ xwh, const unsigned* __restrict__ dc)
{
    const int t = blockIdx.x * 256 + threadIdx.x;
    const int row = t >> 3;
    const float dd = rsqrtf(1.0f + (float)(dc[row] & SUM_MASK) * 0x1p-18f);
    half8_t v = *(half8_t*)&xwh[(size_t)t * 8];
#pragma unroll
    for (int i = 0; i < 8; ++i) v[i] = (_Float16)((float)v[i] * dd);
    *(half8_t*)&xwh[(size_t)t * 8] = v;
}

__global__ __launch_bounds__(256) void k_gather(
    const _Float16* __restrict__ xws, const unsigned* __restrict__ dc,
    const unsigned* __restrict__ se32, float* __restrict__ S)
{
    const int tid  = threadIdx.x;
    const int lane = tid & 63;
    const int wv   = tid >> 6;
    const int d0   = blockIdx.x * ROWS_PER_BLOCK + wv * ROWS_PER_WAVE;

    unsigned pk[ROWS_PER_WAVE];
    float    sf[ROWS_PER_WAVE];
#pragma unroll
    for (int i = 0; i < ROWS_PER_WAVE; ++i) pk[i] = dc[d0 + i];
#pragma unroll
    for (int i = 0; i < ROWS_PER_WAVE; ++i)
        sf[i] = (float)xws[(size_t)(d0 + i) * HDIM + lane];

    float acc = 0.f;
#pragma unroll
    for (int i = 0; i < ROWS_PER_WAVE; ++i) {
        const int d = d0 + i;
        const float dd = rsqrtf(1.0f + (float)(pk[i] & SUM_MASK) * 0x1p-18f);
        int cnt = (int)(pk[i] >> CNT_SHIFT);
        cnt = cnt < SLOTS ? cnt : SLOTS;
        const unsigned* bkt = se32 + (size_t)d * SLOTS;

        float a0 = sf[i];
        float a1 = 0.f, a2 = 0.f, a3 = 0.f;
        int j = 0;
        for (; j + 8 <= cnt; j += 8) {
            uint4 qa = *(const uint4*)(bkt + j);
            uint4 qb = *(const uint4*)(bkt + j + 4);
            float v0 = (float)xws[(size_t)(qa.x >> 15) * HDIM + lane];
            float v1 = (float)xws[(size_t)(qa.y >> 15) * HDIM + lane];
            float v2 = (float)xws[(size_t)(qa.z >> 15) * HDIM + lane];
            float v3 = (float)xws[(size_t)(qa.w >> 15) * HDIM + lane];
            float v4 = (float)xws[(size_t)(qb.x >> 15) * HDIM + lane];
            float v5 = (float)xws[(size_t)(qb.y >> 15) * HDIM + lane];
            float v6 = (float)xws[(size_t)(qb.z >> 15) * HDIM + lane];
            float v7 = (float)xws[(size_t)(qb.w >> 15) * HDIM + lane];
            a0 = fmaf((float)(qa.x & 0x7FFFu) * 0x1p-15f, v0, a0);
            a1 = fmaf((float)(qa.y & 0x7FFFu) * 0x1p-15f, v1, a1);
            a2 = fmaf((float)(qa.z & 0x7FFFu) * 0x1p-15f, v2, a2);
            a3 = fmaf((float)(qa.w & 0x7FFFu) * 0x1p-15f, v3, a3);
            a0 = fmaf((float)(qb.x & 0x7FFFu) * 0x1p-15f, v4, a0);
            a1 = fmaf((float)(qb.y & 0x7FFFu) * 0x1p-15f, v5, a1);
            a2 = fmaf((float)(qb.z & 0x7FFFu) * 0x1p-15f, v6, a2);
            a3 = fmaf((float)(qb.w & 0x7FFFu) * 0x1p-15f, v7, a3);
        }
        for (; j + 4 <= cnt; j += 4) {
            uint4 q = *(const uint4*)(bkt + j);
            float v0 = (float)xws[(size_t)(q.x >> 15) * HDIM + lane];
            float v1 = (float)xws[(size_t)(q.y >> 15) * HDIM + lane];
            float v2 = (float)xws[(size_t)(q.z >> 15) * HDIM + lane];
            float v3 = (float)xws[(size_t)(q.w >> 15) * HDIM + lane];
            a0 = fmaf((float)(q.x & 0x7FFFu) * 0x1p-15f, v0, a0);
            a1 = fmaf((float)(q.y & 0x7FFFu) * 0x1p-15f, v1, a1);
            a2 = fmaf((float)(q.z & 0x7FFFu) * 0x1p-15f, v2, a2);
            a3 = fmaf((float)(q.w & 0x7FFFu) * 0x1p-15f, v3, a3);
        }
        for (; j < cnt; ++j) {
            unsigned u = bkt[j];
            a0 = fmaf((float)(u & 0x7FFFu) * 0x1p-15f,
                      (float)xws[(size_t)(u >> 15) * HDIM + lane], a0);
        }
        acc = fmaf(dd, (a0 + a1) + (a2 + a3), acc);
    }

    __shared__ float red[256];
    red[tid] = acc;
    __syncthreads();
    if (tid < 64) {
        float s = red[tid] + red[64 + tid] + red[128 + tid] + red[192 + tid];
        atomicAdd(&S[((blockIdx.x * ROWS_PER_BLOCK) / NNEUR) * HDIM + tid], s);
    }
}

// =================== shared final head =====================================
__global__ __launch_bounds__(256) void k_final(
    const float* __restrict__ S, const float* __restrict__ W1,
    const float* __restrict__ W2, const float* __restrict__ fcW,
    const float* __restrict__ fcb, float* __restrict__ out)
{
    __shared__ float xt[256];
    __shared__ float a1[128];
    __shared__ float attn[256];
    __shared__ float pooled[512];
    const int tid = threadIdx.x;

    {
        float s = 0.f;
        const float* p = S + tid * 64;
#pragma unroll
        for (int hh = 0; hh < 64; ++hh) s += p[hh];
        xt[tid] = s * (1.0f / 32000.0f);
    }
    __syncthreads();
    if (tid < 128) {
        int b = tid >> 4, i = tid & 15;
        float s = 0.f;
#pragma unroll
        for (int t = 0; t < 32; ++t) s += xt[b * 32 + t] * W1[i * 32 + t];
        a1[tid] = fmaxf(s, 0.f);
    }
    __syncthreads();
    {
        int b = tid >> 5, t = tid & 31;
        float s = 0.f;
#pragma unroll
        for (int i = 0; i < 16; ++i) s += a1[b * 16 + i] * W2[t * 16 + i];
        attn[tid] = 1.0f / (1.0f + __expf(-s));
    }
    __syncthreads();
    for (int o = tid; o < 512; o += 256) {
        int b = o >> 6, h = o & 63;
        float s = 0.f;
#pragma unroll
        for (int t = 0; t < 32; ++t) s += attn[b * 32 + t] * S[(b * 32 + t) * 64 + h];
        pooled[o] = s;
    }
    __syncthreads();
    if (tid < BATCHB * NSTEPS) {
        int b = tid / NSTEPS, st = tid % NSTEPS;
        float acc = fcb[st];
#pragma unroll
        for (int h = 0; h < 64; ++h) acc += pooled[b * 64 + h] * fcW[st * 64 + h];
        out[b * NSTEPS + st] = acc;
    }
}

extern "C" void kernel_launch(void* const* d_in, const int* in_sizes, int n_in,
                              void* d_out, int out_size, void* d_ws, size_t ws_size,
                              hipStream_t stream) {
    const float* x   = (const float*)d_in[0];
    const int*   ei  = (const int*)  d_in[1];
    const float* ea  = (const float*)d_in[2];
    const float* Wih = (const float*)d_in[4];
    const float* Whh = (const float*)d_in[5];
    const float* bih = (const float*)d_in[6];
    const float* bhh = (const float*)d_in[7];
    const float* Wg  = (const float*)d_in[8];
    const float* W1  = (const float*)d_in[9];
    const float* W2  = (const float*)d_in[10];
    const float* fcW = (const float*)d_in[11];
    const float* fcb = (const float*)d_in[12];
    float* out = (float*)d_out;

    if (ws_size >= (size_t)MAIN_WS) {
        // ---- main M-GEMM pipeline (99.3 MB) ----
        char* p = (char*)d_ws;
        float* dw = (float*)p;         p += 512000;
        float* S  = (float*)p;         p += 65536;
        char*  M  = p;                 p += MBYTES;           // 65.536 MB
        float* Ppart = (float*)p;      p += sizeof(float) * GEMM_BLOCKS * PPART;  // 16.78 MB
        _Float16* xwh = (_Float16*)p;                          // 16.38 MB

        (void)hipMemsetAsync(dw, 0, 512000, stream);
        k_recHZ  <<<REC_BLOCKS + HISTF_BLOCKS + ZERO_BLOCKS, 256, 0, stream>>>(
            x, Wih, Whh, bih, bhh, Wg, xwh, ei, ea, dw, (uint4*)M);
        k_scaleF <<<SCALE_BLOCKS, 256, 0, stream>>>(xwh, dw);
        k_Mbuild <<<MB_BLOCKS, 256, 0, stream>>>(ei, ea, dw, (unsigned*)M);
        k_gemm   <<<GEMM_BLOCKS, 512, 0, stream>>>(xwh, (const unsigned short*)M, Ppart);
        k_mergeM <<<NBT, 256, 0, stream>>>(Ppart, xwh, dw, S);
        k_final  <<<1, 256, 0, stream>>>(S, W1, W2, fcW, fcb, out);
    } else {
        // ---- fallback: r6 bucket pipeline (33.3 MB) ----
        char* p = (char*)d_ws;
        unsigned* dc = (unsigned*)p;   p += sizeof(unsigned) * NTOT;
        float* S = (float*)p;          p += sizeof(float) * 256 * HDIM;
        unsigned* se32 = (unsigned*)p; p += sizeof(unsigned) * (size_t)NTOT * SLOTS;
        _Float16* xwh = (_Float16*)p;

        (void)hipMemsetAsync(dc, 0, sizeof(unsigned) * NTOT + sizeof(float) * 256 * HDIM, stream);
        k_recHist <<<REC_BLOCKS + HIST_BLOCKS, 256, 0, stream>>>(
            x, Wih, Whh, bih, bhh, Wg, xwh, ei, ea, dc, se32);
        k_scale   <<<SCALE_BLOCKS, 256, 0, stream>>>(xwh, dc);
        k_gather  <<<GATHER_BLOCKS, 256, 0, stream>>>(xwh, dc, se32, S);
        k_final   <<<1, 256, 0, stream>>>(S, W1, W2, fcW, fcb, out);
    }
}

// Round 12
// 234.594 us; speedup vs baseline: 1.7574x; 1.7574x over previous
//
#include <hip/hip_runtime.h>
#include <hip/hip_fp16.h>

#define NNODES   4000
#define TSTEPS   32
#define HDIM     64
#define ECOUNT   1024000
#define NTOT     128000        // NNODES * TSTEPS
#define BATCHB   8
#define NNEUR    500
#define TEBD     16
#define NSTEPS   12

// packed u32 histogram cell: count in [31:23] (<=511), sum(w) fixed-point
// 2^-18 in [22:0] (max 32.0, needs 5 int bits; deg err <= ~2e-5, harmless)
#define CNT_SHIFT 23
#define SUM_MASK  0x7FFFFFu
#define SUM_SCALE 262144.0f    // 2^18
#define SLOTS     32           // fixed bucket stride; P(indeg>32) ~ 1e-10 (Poisson mean 8)
#define REC_BLOCKS  (NNODES / 16)    // 250
#define HIST_BLOCKS (ECOUNT / 256)   // 4000: 1 edge/thread (2/thread was -20us, round 4)
#define SCALE_BLOCKS (NTOT * HDIM / 8 / 256)  // 4000

#define ROWS_PER_WAVE  5       // gather: rows per wave; 20 rows/block, 20 | 500
#define ROWS_PER_BLOCK 20
#define GATHER_BLOCKS  (NTOT / ROWS_PER_BLOCK)   // 6400

typedef _Float16 half8_t __attribute__((ext_vector_type(8)));
typedef float    f32x4_t __attribute__((ext_vector_type(4)));

__device__ __forceinline__ float sigmoidf_(float x) {
    return 1.0f / (1.0f + __expf(-x));
}
__device__ __forceinline__ float tanhf_(float x) {
    return 1.0f - 2.0f / (1.0f + __expf(2.0f * x));
}

// ---------------- fused: MFMA GRU recurrence (blocks 0..249) +
//                  packed degree/count histogram (blocks 250..4249) --------
// FINAL STRUCTURE (falsification ledger, rounds 2-11): the bucket scatter
// (~65 MB line-granular cross-XCD writes) and the random row gather are
// TRANSACTION-priced, not byte-priced. Falsified alternatives: smaller
// payload (r4), cross-XCD write merging (r2/r4: doesn't exist), XCD-local
// sharding (r9: worse), unordered LDS edge-centric (r5: 386us, r8: 362us,
// occupancy-capped by the LDS accumulator), dense M-GEMM (r11: 412us,
// traffic-multiplied). No fences in hot paths (r3: buffer_inv storm).
// Histogram: one u32 atomic per edge packs sum(w) fixed-point + count; the
// returned old value's count IS the edge's rank in its dst bucket -> direct
// write se32[d*SLOTS+rank]. Entry is 4 B: (s:17 | w:15 fixed 2^-15).
// Recurrence: one block (4 waves) owns 16 nodes for all 32 timesteps; wave
// wv owns the 16-feature stripe of each gate. Weight B-frags in VGPRs; LDS
// only a 2x(16x72) fp16 ping-pong for the C->A h transpose; 1 barrier/step.
// Fragment layouts (gfx950 16x16x32): A[m=lane&15][k=quad*8+j],
// B[k=quad*8+j][n=lane&15], C[m=quad*4+reg][n=lane&15].
__global__ __launch_bounds__(256) void k_recHist(
    const float* __restrict__ x, const float* __restrict__ Wih,
    const float* __restrict__ Whh, const float* __restrict__ bih,
    const float* __restrict__ bhh, const float* __restrict__ Wg,
    _Float16* __restrict__ xwh,
    const int* __restrict__ ei, const float* __restrict__ ea,
    unsigned* __restrict__ dc, unsigned* __restrict__ se32)
{
    __shared__ __align__(16) _Float16 hbuf[2][16 * 72];   // stride 72: conflict-free

    const int tid = threadIdx.x;

    if (blockIdx.x >= REC_BLOCKS) {
        // -------- histogram path: 1 edge per thread --------
        int e = (blockIdx.x - REC_BLOCKS) * 256 + tid;   // covers exactly ECOUNT
        int s = ei[e], d = ei[ECOUNT + e];
        float w = ea[e];
        unsigned q = (unsigned)(w * 32768.0f + 0.5f); q = q > 32767u ? 32767u : q;
        unsigned fx = (unsigned)(w * SUM_SCALE + 0.5f);
        unsigned old = atomicAdd(&dc[d], (1u << CNT_SHIFT) | fx);
        int r = (int)(old >> CNT_SHIFT);
        if (r < SLOTS)   // safety clamp; statistically never taken
            se32[d * SLOTS + r] = ((unsigned)s << 15) | q;
        return;
    }

    // -------- recurrence path --------
    const int lane = tid & 63;
    const int wv   = tid >> 6;       // feature tile 0..3
    const int c    = lane & 15;
    const int quad = lane >> 4;
    const int n0   = blockIdx.x * 16;

    auto makeB = [&](const float* W, int row, int k0) -> half8_t {
        const float4* p = (const float4*)(W + (size_t)row * HDIM + k0);
        float4 u = p[0], v = p[1];
        half8_t h;
        h[0] = (_Float16)u.x; h[1] = (_Float16)u.y; h[2] = (_Float16)u.z; h[3] = (_Float16)u.w;
        h[4] = (_Float16)v.x; h[5] = (_Float16)v.y; h[6] = (_Float16)v.z; h[7] = (_Float16)v.w;
        return h;
    };

    half8_t Bxr[2], Bxz[2], Bxn[2], Bhr[2], Bhz[2], Bhn[2], Bw[2];
#pragma unroll
    for (int kt = 0; kt < 2; ++kt) {
        int k0 = kt * 32 + quad * 8;
        Bxr[kt] = makeB(Wih, wv * 16 + c, k0);
        Bxz[kt] = makeB(Wih, 64 + wv * 16 + c, k0);
        Bxn[kt] = makeB(Wih, 128 + wv * 16 + c, k0);
        Bhr[kt] = makeB(Whh, wv * 16 + c, k0);
        Bhz[kt] = makeB(Whh, 64 + wv * 16 + c, k0);
        Bhn[kt] = makeB(Whh, 128 + wv * 16 + c, k0);
        Bw[kt]  = makeB(Wg, wv * 16 + c, k0);
    }

    const int f = wv * 16 + c;
    const float brz_r = bih[f] + bhh[f];
    const float brz_z = bih[64 + f] + bhh[64 + f];
    const float bin_  = bih[128 + f];
    const float bhn_  = bhh[128 + f];

    float hreg[4] = {0.f, 0.f, 0.f, 0.f};
    half8_t ah[2];

    const float* xp = x + (size_t)(n0 + c) * (TSTEPS * HDIM) + quad * 8;

    float4 xq0[4], xq1[4];
    {
        const float* p0 = xp;
        xq0[0] = *(const float4*)(p0);      xq0[1] = *(const float4*)(p0 + 4);
        xq0[2] = *(const float4*)(p0 + 32); xq0[3] = *(const float4*)(p0 + 36);
        const float* p1 = xp + HDIM;
        xq1[0] = *(const float4*)(p1);      xq1[1] = *(const float4*)(p1 + 4);
        xq1[2] = *(const float4*)(p1 + 32); xq1[3] = *(const float4*)(p1 + 36);
    }

    auto step = [&](int t, float4* xq) {
        half8_t ax[2];
#pragma unroll
        for (int kt = 0; kt < 2; ++kt) {
            float4 u = xq[kt * 2], v = xq[kt * 2 + 1];
            half8_t a;
            a[0] = (_Float16)u.x; a[1] = (_Float16)u.y; a[2] = (_Float16)u.z; a[3] = (_Float16)u.w;
            a[4] = (_Float16)v.x; a[5] = (_Float16)v.y; a[6] = (_Float16)v.z; a[7] = (_Float16)v.w;
            ax[kt] = a;
        }
        if (t + 2 < TSTEPS) {
            const float* pt = xp + (size_t)(t + 2) * HDIM;
            xq[0] = *(const float4*)(pt);      xq[1] = *(const float4*)(pt + 4);
            xq[2] = *(const float4*)(pt + 32); xq[3] = *(const float4*)(pt + 36);
        }

        f32x4_t Cr  = (f32x4_t){0.f, 0.f, 0.f, 0.f};
        f32x4_t Cz  = (f32x4_t){0.f, 0.f, 0.f, 0.f};
        f32x4_t Cnx = (f32x4_t){0.f, 0.f, 0.f, 0.f};
        f32x4_t Cnh = (f32x4_t){0.f, 0.f, 0.f, 0.f};

#pragma unroll
        for (int kt = 0; kt < 2; ++kt) {
            Cr  = __builtin_amdgcn_mfma_f32_16x16x32_f16(ax[kt], Bxr[kt], Cr, 0, 0, 0);
            Cz  = __builtin_amdgcn_mfma_f32_16x16x32_f16(ax[kt], Bxz[kt], Cz, 0, 0, 0);
            Cnx = __builtin_amdgcn_mfma_f32_16x16x32_f16(ax[kt], Bxn[kt], Cnx, 0, 0, 0);
        }
        if (t > 0) {
#pragma unroll
            for (int kt = 0; kt < 2; ++kt) {
                Cr  = __builtin_amdgcn_mfma_f32_16x16x32_f16(ah[kt], Bhr[kt], Cr, 0, 0, 0);
                Cz  = __builtin_amdgcn_mfma_f32_16x16x32_f16(ah[kt], Bhz[kt], Cz, 0, 0, 0);
                Cnh = __builtin_amdgcn_mfma_f32_16x16x32_f16(ah[kt], Bhn[kt], Cnh, 0, 0, 0);
            }
        }

        _Float16* hb = hbuf[t & 1];
#pragma unroll
        for (int r = 0; r < 4; ++r) {
            float rr = sigmoidf_(Cr[r] + brz_r);
            float zz = sigmoidf_(Cz[r] + brz_z);
            float nn = tanhf_(Cnx[r] + bin_ + rr * (Cnh[r] + bhn_));
            float hn = (1.0f - zz) * nn + zz * hreg[r];
            hreg[r] = hn;
            hb[(quad * 4 + r) * 72 + f] = (_Float16)hn;
        }

        __syncthreads();

#pragma unroll
        for (int kt = 0; kt < 2; ++kt)
            ah[kt] = *(half8_t*)&hb[c * 72 + kt * 32 + quad * 8];

        f32x4_t Cw = (f32x4_t){0.f, 0.f, 0.f, 0.f};
#pragma unroll
        for (int kt = 0; kt < 2; ++kt)
            Cw = __builtin_amdgcn_mfma_f32_16x16x32_f16(ah[kt], Bw[kt], Cw, 0, 0, 0);

#pragma unroll
        for (int r = 0; r < 4; ++r) {
            int row = (n0 + quad * 4 + r) * TSTEPS + t;
            xwh[(size_t)row * HDIM + f] = (_Float16)Cw[r];
        }
    };

#pragma unroll 1
    for (int tt = 0; tt < TSTEPS; tt += 2) {
        step(tt, xq0);
        step(tt + 1, xq1);
    }
}

// ---------------- in-place pre-scale: xwh[r][:] *= dis[r] -----------------
// dis[r] = rsqrt(1 + sum_w) from the packed dc. After this pass the gather
// needs NO per-src dc lookup: y[d] = dis[d]*(xws[d] + sum_e w_e*xws[src_e]).
// BW-bound: ~33 MB, ~8 us.
__global__ __launch_bounds__(256) void k_scale(
    _Float16* __restrict__ xwh, const unsigned* __restrict__ dc)
{
    const int t = blockIdx.x * 256 + threadIdx.x;      // 8 fp16 per thread
    const int row = t >> 3;
    const float dd = rsqrtf(1.0f + (float)(dc[row] & SUM_MASK) * 0x1p-18f);
    half8_t v = *(half8_t*)&xwh[(size_t)t * 8];
#pragma unroll
    for (int i = 0; i < 8; ++i) v[i] = (_Float16)((float)v[i] * dd);
    *(half8_t*)&xwh[(size_t)t * 8] = v;
}

// ---------------- bucket gather fused with per-(b,t) reduction ------------
// Each wave owns ROWS_PER_WAVE=5 consecutive dst rows (block: 20 rows; 20|500
// so a block never straddles a bt bucket). One accumulator per wave across
// its rows -> 64 S-atomics per block (25-way collisions). Inner loop per
// edge is just bucket->row-load->fma (coef packed in the bucket entry; src
// rows pre-scaled by k_scale). 8-way unroll (mean deg = 8) keeps up to 8
// independent 128 B row loads in flight per wave. No fences.
__global__ __launch_bounds__(256) void k_gather(
    const _Float16* __restrict__ xws, const unsigned* __restrict__ dc,
    const unsigned* __restrict__ se32, float* __restrict__ S)
{
    const int tid  = threadIdx.x;
    const int lane = tid & 63;
    const int wv   = tid >> 6;
    const int d0   = blockIdx.x * ROWS_PER_BLOCK + wv * ROWS_PER_WAVE;

    // hoist independent per-row scalars: packed histogram + self-loop value
    unsigned pk[ROWS_PER_WAVE];
    float    sf[ROWS_PER_WAVE];
#pragma unroll
    for (int i = 0; i < ROWS_PER_WAVE; ++i) pk[i] = dc[d0 + i];
#pragma unroll
    for (int i = 0; i < ROWS_PER_WAVE; ++i)
        sf[i] = (float)xws[(size_t)(d0 + i) * HDIM + lane];

    float acc = 0.f;
#pragma unroll
    for (int i = 0; i < ROWS_PER_WAVE; ++i) {
        const int d = d0 + i;
        const float dd = rsqrtf(1.0f + (float)(pk[i] & SUM_MASK) * 0x1p-18f);
        int cnt = (int)(pk[i] >> CNT_SHIFT);
        cnt = cnt < SLOTS ? cnt : SLOTS;
        const unsigned* bkt = se32 + (size_t)d * SLOTS;

        float a0 = sf[i];        // self-loop term: xws[d] (dd applied at end)
        float a1 = 0.f, a2 = 0.f, a3 = 0.f;
        int j = 0;
        for (; j + 8 <= cnt; j += 8) {
            uint4 qa = *(const uint4*)(bkt + j);
            uint4 qb = *(const uint4*)(bkt + j + 4);
            float v0 = (float)xws[(size_t)(qa.x >> 15) * HDIM + lane];
            float v1 = (float)xws[(size_t)(qa.y >> 15) * HDIM + lane];
            float v2 = (float)xws[(size_t)(qa.z >> 15) * HDIM + lane];
            float v3 = (float)xws[(size_t)(qa.w >> 15) * HDIM + lane];
            float v4 = (float)xws[(size_t)(qb.x >> 15) * HDIM + lane];
            float v5 = (float)xws[(size_t)(qb.y >> 15) * HDIM + lane];
            float v6 = (float)xws[(size_t)(qb.z >> 15) * HDIM + lane];
            float v7 = (float)xws[(size_t)(qb.w >> 15) * HDIM + lane];
            a0 = fmaf((float)(qa.x & 0x7FFFu) * 0x1p-15f, v0, a0);
            a1 = fmaf((float)(qa.y & 0x7FFFu) * 0x1p-15f, v1, a1);
            a2 = fmaf((float)(qa.z & 0x7FFFu) * 0x1p-15f, v2, a2);
            a3 = fmaf((float)(qa.w & 0x7FFFu) * 0x1p-15f, v3, a3);
            a0 = fmaf((float)(qb.x & 0x7FFFu) * 0x1p-15f, v4, a0);
            a1 = fmaf((float)(qb.y & 0x7FFFu) * 0x1p-15f, v5, a1);
            a2 = fmaf((float)(qb.z & 0x7FFFu) * 0x1p-15f, v6, a2);
            a3 = fmaf((float)(qb.w & 0x7FFFu) * 0x1p-15f, v7, a3);
        }
        for (; j + 4 <= cnt; j += 4) {
            uint4 q = *(const uint4*)(bkt + j);
            float v0 = (float)xws[(size_t)(q.x >> 15) * HDIM + lane];
            float v1 = (float)xws[(size_t)(q.y >> 15) * HDIM + lane];
            float v2 = (float)xws[(size_t)(q.z >> 15) * HDIM + lane];
            float v3 = (float)xws[(size_t)(q.w >> 15) * HDIM + lane];
            a0 = fmaf((float)(q.x & 0x7FFFu) * 0x1p-15f, v0, a0);
            a1 = fmaf((float)(q.y & 0x7FFFu) * 0x1p-15f, v1, a1);
            a2 = fmaf((float)(q.z & 0x7FFFu) * 0x1p-15f, v2, a2);
            a3 = fmaf((float)(q.w & 0x7FFFu) * 0x1p-15f, v3, a3);
        }
        for (; j < cnt; ++j) {
            unsigned u = bkt[j];
            a0 = fmaf((float)(u & 0x7FFFu) * 0x1p-15f,
                      (float)xws[(size_t)(u >> 15) * HDIM + lane], a0);
        }
        acc = fmaf(dd, (a0 + a1) + (a2 + a3), acc);
    }

    __shared__ float red[256];
    red[tid] = acc;
    __syncthreads();
    if (tid < 64) {
        float s = red[tid] + red[64 + tid] + red[128 + tid] + red[192 + tid];
        atomicAdd(&S[((blockIdx.x * ROWS_PER_BLOCK) / NNEUR) * HDIM + tid], s);  // bt = d/500
    }
}

// ---------------- attention MLP + pooling + FC head (one block) ----------------
__global__ __launch_bounds__(256) void k_final(
    const float* __restrict__ S, const float* __restrict__ W1,
    const float* __restrict__ W2, const float* __restrict__ fcW,
    const float* __restrict__ fcb, float* __restrict__ out)
{
    __shared__ float xt[256];
    __shared__ float a1[128];
    __shared__ float attn[256];
    __shared__ float pooled[512];
    const int tid = threadIdx.x;

    {
        float s = 0.f;
        const float* p = S + tid * 64;
#pragma unroll
        for (int hh = 0; hh < 64; ++hh) s += p[hh];
        xt[tid] = s * (1.0f / 32000.0f);
    }
    __syncthreads();
    if (tid < 128) {
        int b = tid >> 4, i = tid & 15;
        float s = 0.f;
#pragma unroll
        for (int t = 0; t < 32; ++t) s += xt[b * 32 + t] * W1[i * 32 + t];
        a1[tid] = fmaxf(s, 0.f);
    }
    __syncthreads();
    {
        int b = tid >> 5, t = tid & 31;
        float s = 0.f;
#pragma unroll
        for (int i = 0; i < 16; ++i) s += a1[b * 16 + i] * W2[t * 16 + i];
        attn[tid] = 1.0f / (1.0f + __expf(-s));
    }
    __syncthreads();
    for (int o = tid; o < 512; o += 256) {
        int b = o >> 6, h = o & 63;
        float s = 0.f;
#pragma unroll
        for (int t = 0; t < 32; ++t) s += attn[b * 32 + t] * S[(b * 32 + t) * 64 + h];
        pooled[o] = s;
    }
    __syncthreads();
    if (tid < BATCHB * NSTEPS) {
        int b = tid / NSTEPS, st = tid % NSTEPS;
        float acc = fcb[st];
#pragma unroll
        for (int h = 0; h < 64; ++h) acc += pooled[b * 64 + h] * fcW[st * 64 + h];
        out[b * NSTEPS + st] = acc;
    }
}

extern "C" void kernel_launch(void* const* d_in, const int* in_sizes, int n_in,
                              void* d_out, int out_size, void* d_ws, size_t ws_size,
                              hipStream_t stream) {
    const float* x   = (const float*)d_in[0];
    const int*   ei  = (const int*)  d_in[1];
    const float* ea  = (const float*)d_in[2];
    // d_in[3] = batch: unused by the reference computation
    const float* Wih = (const float*)d_in[4];
    const float* Whh = (const float*)d_in[5];
    const float* bih = (const float*)d_in[6];
    const float* bhh = (const float*)d_in[7];
    const float* Wg  = (const float*)d_in[8];
    const float* W1  = (const float*)d_in[9];
    const float* W2  = (const float*)d_in[10];
    const float* fcW = (const float*)d_in[11];
    const float* fcb = (const float*)d_in[12];
    float* out = (float*)d_out;

    // workspace layout (~33.3 MB); dc and S adjacent -> one memset clears both
    char* p = (char*)d_ws;
    unsigned* dc = (unsigned*)p;   p += sizeof(unsigned) * NTOT;                                    // 512 KB
    float* S = (float*)p;          p += sizeof(float) * 256 * HDIM;                                 // 64 KB
    unsigned* se32 = (unsigned*)p; p += sizeof(unsigned) * (size_t)NTOT * SLOTS;                    // 16.38 MB
    _Float16* xwh = (_Float16*)p;  p += sizeof(_Float16) * (size_t)NTOT * HDIM;                     // 16.38 MB

    (void)hipMemsetAsync(dc, 0, sizeof(unsigned) * NTOT + sizeof(float) * 256 * HDIM, stream);
    k_recHist <<<REC_BLOCKS + HIST_BLOCKS, 256, 0, stream>>>(
        x, Wih, Whh, bih, bhh, Wg, xwh, ei, ea, dc, se32);
    k_scale   <<<SCALE_BLOCKS, 256, 0, stream>>>(xwh, dc);
    k_gather  <<<GATHER_BLOCKS, 256, 0, stream>>>(xwh, dc, se32, S);
    k_final   <<<1, 256, 0, stream>>>(S, W1, W2, fcW, fcb, out);
}